// Round 8
// baseline (213.533 us; speedup 1.0000x reference)
//
#include <hip/hip_runtime.h>

#define NROWS 8192
#define BQ    4096
#define DDIM  256
#define INV_T (1.0f/0.07f)
#define K2EXP (1.4426950408889634f/0.07f)   // log2(e)/T
#define NTILE 64                            // 8192/128 row tiles
#define NBLK  (NTILE*(NTILE+1)/2)           // 2080 lower-tri tiles

typedef short bf16x8 __attribute__((ext_vector_type(8)));
typedef float f32x4  __attribute__((ext_vector_type(4)));
typedef unsigned short u16;

__device__ __forceinline__ u16 f2bf(float f) {
  unsigned u = __float_as_uint(f);
  u += 0x7fffu + ((u >> 16) & 1u);   // round-to-nearest-even
  return (u16)(u >> 16);
}

// ---------------- kernel 1: L2-normalize rows -> bf16; zero partials ---------
__global__ void norm_cast_kernel(const float* __restrict__ zi,
                                 const float* __restrict__ zj,
                                 u16* __restrict__ zb,
                                 float* __restrict__ partials) {
  int wave = threadIdx.x >> 6;
  int lane = threadIdx.x & 63;
  int row  = blockIdx.x * 4 + wave;            // one wave per row, 4 rows/block
  const float* src = (row < BQ) ? (zi + (size_t)row * DDIM)
                                : (zj + (size_t)(row - BQ) * DDIM);
  float4 v = ((const float4*)src)[lane];       // 64 lanes x float4 = 256
  float s = v.x*v.x + v.y*v.y + v.z*v.z + v.w*v.w;
  #pragma unroll
  for (int m = 32; m; m >>= 1) s += __shfl_xor(s, m, 64);
  float scale = 1.0f / fmaxf(sqrtf(s), 1e-12f);
  ushort4 o;
  o.x = f2bf(v.x * scale); o.y = f2bf(v.y * scale);
  o.z = f2bf(v.z * scale); o.w = f2bf(v.w * scale);
  ((ushort4*)(zb + (size_t)row * DDIM))[lane] = o;
  // zero pos_p||neg_p (2*8192 floats) for simloss atomicAdd: 8 per block
  if (threadIdx.x < 8)
    partials[(size_t)blockIdx.x * 8 + threadIdx.x] = 0.0f;
}

// ---------------- kernel 2: triangular fused sim GEMM + pos/negexp scatter ---
#define GL2LDS(gp, lp) \
  __builtin_amdgcn_global_load_lds((__attribute__((address_space(1))) void*)(gp), \
                                   (__attribute__((address_space(3))) void*)(lp), 16, 0, 0)

// NOTE (round 2): never add a min-waves arg to __launch_bounds__ — clamping
// the unified VGPR+AGPR file spills the accumulator (620 MB HBM, 63->160us).
// NOTE (rounds 4/6): co-residency is pinned at 2 blocks/CU for VGPR in
// [128,~190] (unified 512/(vgpr+64agpr)); grid size beyond that is neutral.
// LDS-combine epilogues regress (R4); shuffle+atomicAdd epilogues are fine (R6).
// NOTE (round 5): no-barrier K-loop w/ register-B regressed (latency exposed).
// NOTE (round 7): hipLaunchCooperativeKernel fails at grid=512 (co-residency
// validation); total-simloss gap is a FIXED ~65us replay cost, not per-node.
// Round 8: sim is symmetric — compute only lower-tri tiles (2080/4096),
// scatter each entry to BOTH row and col sums. Halves MFMA/LDS/staging.
__global__ __launch_bounds__(256) void simloss_kernel(
    const u16* __restrict__ zb, const int* __restrict__ labels,
    float* __restrict__ pos_p, float* __restrict__ neg_p) {
  // row-major [128][32] bf16, chunk-SWIZZLED: row r's 8-elt chunk c lives at
  // slot c ^ ((r>>1)&3) -> 2-way bank aliasing = free.
  // (measured rounds 2/3: SQ_LDS_BANK_CONFLICT 4.19M -> 0)
  __shared__ __align__(16) u16 lsA[128 * 32];
  __shared__ __align__(16) u16 lsB[128 * 32];

  const int tid  = threadIdx.x;
  const int w    = tid >> 6;         // wave 0..3
  const int lane = tid & 63;
  const int ln   = lane & 15;        // MFMA n/m lane index
  const int qd   = lane >> 4;        // MFMA quad
  const int wr   = w >> 1;           // wave row (0..1) in 2x2 wave grid
  const int wc   = w & 1;            // wave col

  // decode bid -> (bx, by), by <= bx, bid = bx(bx+1)/2 + by
  int bid = blockIdx.x;
  int bx = (int)((sqrtf(8.0f * (float)bid + 1.0f) - 1.0f) * 0.5f);
  while ((bx + 1) * (bx + 2) / 2 <= bid) ++bx;
  while (bx * (bx + 1) / 2 > bid) --bx;
  int by = bid - bx * (bx + 1) / 2;
  const bool offdiag = (bx != by);
  const int r0 = bx * 128;           // row tile base
  const int c0 = by * 128;           // col tile base (c0 <= r0)

  const int strow = lane >> 2;       // staging: 16 rows per load instr
  const int slot  = lane & 3;        // LDS chunk position this lane fills
  const int stk   = (slot ^ ((strow >> 1) & 3)) * 8;  // global chunk to fetch
  const int rdsw  = (ln >> 1) & 3;   // read-side swizzle key

  int rowidx[16], rowlab[16];
  #pragma unroll
  for (int ri = 0; ri < 4; ++ri)
    #pragma unroll
    for (int r = 0; r < 4; ++r) {
      int slt = ri * 4 + r;
      int row = r0 + wr * 64 + ri * 16 + qd * 4 + r;   // C/D: row = quad*4+reg
      rowidx[slt] = row;
      rowlab[slt] = labels[row & (BQ - 1)];            // concat labels = labels[row % B]
    }
  int colv[4], clab[4];
  #pragma unroll
  for (int mi = 0; mi < 4; ++mi) {
    colv[mi] = c0 + wc * 64 + mi * 16 + ln;            // C/D: col = lane&15
    clab[mi] = labels[colv[mi] & (BQ - 1)];
  }

  const f32x4 z4 = {0.f, 0.f, 0.f, 0.f};
  f32x4 acc[4][4];
  #pragma unroll
  for (int ri = 0; ri < 4; ++ri)
    #pragma unroll
    for (int mi = 0; mi < 4; ++mi) acc[ri][mi] = z4;

  for (int kk = 0; kk < 8; ++kk) {             // K = 256, BK = 32
    const int k0 = kk * 32;
    #pragma unroll
    for (int j = 0; j < 2; ++j) {              // wave stages 32 rows of A and B
      int rbase = w * 32 + j * 16;
      const u16* ga = zb + (size_t)(r0 + rbase + strow) * DDIM + k0 + stk;
      GL2LDS(ga, &lsA[rbase * 32]);
      const u16* gb = zb + (size_t)(c0 + rbase + strow) * DDIM + k0 + stk;
      GL2LDS(gb, &lsB[rbase * 32]);
    }
    __syncthreads();                           // drains vmcnt before barrier

    bf16x8 av[4], bv[4];
    #pragma unroll
    for (int ri = 0; ri < 4; ++ri)             // A[m=ln][k=qd*8+j], swizzled slot
      av[ri] = *(const bf16x8*)&lsA[(wr * 64 + ri * 16 + ln) * 32 + (qd ^ rdsw) * 8];
    #pragma unroll
    for (int mi = 0; mi < 4; ++mi)             // B[n=ln][k=qd*8+j] (B^T input)
      bv[mi] = *(const bf16x8*)&lsB[(wc * 64 + mi * 16 + ln) * 32 + (qd ^ rdsw) * 8];
    #pragma unroll
    for (int ri = 0; ri < 4; ++ri)
      #pragma unroll
      for (int mi = 0; mi < 4; ++mi)
        acc[ri][mi] = __builtin_amdgcn_mfma_f32_16x16x32_bf16(
            av[ri], bv[mi], acc[ri][mi], 0, 0, 0);
    __syncthreads();
  }

  // epilogue: each entry s at (row,col) contributes to row sums, and (for
  // off-diagonal tiles) identically to col sums — sim is symmetric.
  float posA[16], negA[16];
  #pragma unroll
  for (int i = 0; i < 16; ++i) { posA[i] = 0.0f; negA[i] = 0.0f; }
  float colp[4], coln[4];
  #pragma unroll
  for (int i = 0; i < 4; ++i) { colp[i] = 0.0f; coln[i] = 0.0f; }

  #pragma unroll
  for (int ri = 0; ri < 4; ++ri)
    #pragma unroll
    for (int mi = 0; mi < 4; ++mi) {
      f32x4 v = acc[ri][mi];
      #pragma unroll
      for (int r = 0; r < 4; ++r) {
        int slt = ri * 4 + r;
        float s = v[r];
        bool same = (rowlab[slt] == clab[mi]);
        bool dg   = (rowidx[slt] == colv[mi]);
        float pc = (same && !dg) ? s : 0.0f;
        float nc = same ? 0.0f : __builtin_amdgcn_exp2f(s * K2EXP);
        posA[slt] += pc;  negA[slt] += nc;
        colp[mi]  += pc;  coln[mi]  += nc;     // discarded for diagonal tiles
      }
    }

  // row-side: reduce over the 16 ln lanes (cols of this wave's strip)
  #pragma unroll
  for (int i = 0; i < 16; ++i) {
    #pragma unroll
    for (int m = 1; m < 16; m <<= 1) {
      posA[i] += __shfl_xor(posA[i], m, 64);
      negA[i] += __shfl_xor(negA[i], m, 64);
    }
  }
  if (ln == 0) {
    #pragma unroll
    for (int i = 0; i < 16; ++i) {
      atomicAdd(&pos_p[rowidx[i]], posA[i]);
      atomicAdd(&neg_p[rowidx[i]], negA[i]);
    }
  }

  // col-side (off-diagonal tiles only): reduce over qd (rows of the strip)
  if (offdiag) {
    #pragma unroll
    for (int mi = 0; mi < 4; ++mi) {
      colp[mi] += __shfl_xor(colp[mi], 16, 64);
      colp[mi] += __shfl_xor(colp[mi], 32, 64);
      coln[mi] += __shfl_xor(coln[mi], 16, 64);
      coln[mi] += __shfl_xor(coln[mi], 32, 64);
    }
    if (qd == 0) {
      #pragma unroll
      for (int mi = 0; mi < 4; ++mi) {
        atomicAdd(&pos_p[colv[mi]], colp[mi]);
        atomicAdd(&neg_p[colv[mi]], coln[mi]);
      }
    }
  }
}

// ---------------- kernel 3: per-row loss + mean (single block, no memset) ----
__global__ void loss_kernel(const float* __restrict__ pos_p,
                            const float* __restrict__ neg_p,
                            float* __restrict__ out) {
  int t = threadIdx.x;                           // 1024 threads, 8 rows each
  float lsum = 0.0f;
  #pragma unroll
  for (int rr = 0; rr < 8; ++rr) {
    int row = rr * 1024 + t;
    float p = pos_p[row] * INV_T;
    float n = neg_p[row];
    lsum += log1pf(expf(logf(n) - p));
  }
  #pragma unroll
  for (int m = 32; m; m >>= 1) lsum += __shfl_xor(lsum, m, 64);
  __shared__ float red[16];
  if ((t & 63) == 0) red[t >> 6] = lsum;
  __syncthreads();
  if (t == 0) {
    float tot = 0.0f;
    #pragma unroll
    for (int i = 0; i < 16; ++i) tot += red[i];
    out[0] = tot * (1.0f / NROWS);
  }
}

// ---------------- launcher ---------------------------------------------------
extern "C" void kernel_launch(void* const* d_in, const int* in_sizes, int n_in,
                              void* d_out, int out_size, void* d_ws, size_t ws_size,
                              hipStream_t stream) {
  const float* zi     = (const float*)d_in[0];
  const float* zj     = (const float*)d_in[1];
  const int*   labels = (const int*)d_in[2];
  float*       out    = (float*)d_out;

  char* w = (char*)d_ws;
  u16*   zb    = (u16*)w;                                          // 4 MB bf16 Z
  float* pos_p = (float*)(w + (size_t)NROWS * DDIM * sizeof(u16)); // 8192 f32
  float* neg_p = pos_p + NROWS;                                    // 8192 f32 (contiguous)

  hipLaunchKernelGGL(norm_cast_kernel, dim3(2048), dim3(256), 0, stream,
                     zi, zj, zb, pos_p);
  hipLaunchKernelGGL(simloss_kernel, dim3(NBLK), dim3(256), 0, stream,
                     zb, labels, pos_p, neg_p);
  hipLaunchKernelGGL(loss_kernel, dim3(1), dim3(1024), 0, stream,
                     pos_p, neg_p, out);
}